// Round 5
// baseline (3117.910 us; speedup 1.0000x reference)
//
#include <hip/hip_runtime.h>

#define NLAYER 6
#define NB     128     // batch
#define NT     512     // seq len
#define DIN    128     // layer-0 input size
#define NH     256     // hidden
#define NBLK   192     // 6 layers x 16 slices x 2 batch-groups, all co-resident
#define SLOT_U64 (NB*NH/4)            // ring slot in u64 units (4 bf16 each) = 8192
#define WF_BYTES  (6u*16u*4u*16u*64u*16u)   // 6.29 MB  pre-swizzled weights
#define XF_BYTES  (512u*2u*4u*4u*64u*16u)   // 16.78 MB pre-swizzled x

typedef __attribute__((ext_vector_type(8))) short short8;
typedef __attribute__((ext_vector_type(4))) float f32x4;

__device__ __forceinline__ unsigned f2bf2(float lo, float hi){
  unsigned a = __float_as_uint(lo), b = __float_as_uint(hi);
  a = (a + 0x7fffu + ((a>>16)&1u)) >> 16;   // RNE bf16
  b = (b + 0x7fffu + ((b>>16)&1u)) >> 16;
  return a | (b<<16);
}
__device__ __forceinline__ unsigned long long f2bf4(float a, float b, float c, float d){
  return (unsigned long long)f2bf2(a,b) | ((unsigned long long)f2bf2(c,d) << 32);
}
__device__ __forceinline__ short8 pack16(unsigned long long lo, unsigned long long hi){
  union { unsigned long long u[2]; short8 v; } w; w.u[0]=lo; w.u[1]=hi; return w.v;
}
__device__ __forceinline__ short8 ld8f_frag(const float* p){
  f32x4 a = *(const f32x4*)p;
  f32x4 b = *(const f32x4*)(p+4);
  return pack16(f2bf4(a[0],a[1],a[2],a[3]), f2bf4(b[0],b[1],b[2],b[3]));
}

__device__ __forceinline__ float sigmf(float v){ return 1.0f/(1.0f + __expf(-v)); }
__device__ __forceinline__ float tanhfast(float v){
  v = fminf(fmaxf(v, -15.0f), 15.0f);
  float e = __expf(2.0f*v);
  return (e - 1.0f)/(e + 1.0f);
}

__device__ __forceinline__ int ld_flag(int* p){
  return __hip_atomic_load(p, __ATOMIC_RELAXED, __HIP_MEMORY_SCOPE_AGENT);
}
__device__ __forceinline__ void st_flag(int* p, int v){
  __hip_atomic_store(p, v, __ATOMIC_RELAXED, __HIP_MEMORY_SCOPE_AGENT);
}
__device__ __forceinline__ unsigned long long ring_ld(const unsigned long long* p){
  return __hip_atomic_load(p, __ATOMIC_RELAXED, __HIP_MEMORY_SCOPE_AGENT);
}
__device__ __forceinline__ void ring_st(unsigned long long* p, unsigned long long v){
  __hip_atomic_store(p, v, __ATOMIC_RELAXED, __HIP_MEMORY_SCOPE_AGENT);
}
__device__ __forceinline__ void poll_ge16(int* tp, int val, int lane){
  int guard = 0;
  for (;;){
    int v = (lane < 16) ? ld_flag(tp + lane) : 0x7fffffff;
    if (__ballot(v >= val) == ~0ull) break;
    __builtin_amdgcn_s_sleep(1);
    if (++guard > (1<<22)) break;   // failsafe only
  }
}

// ---------------- prep kernels: one-time swizzle/convert into workspace ----------------
// wf[l][s][q][kt][lane] (16B frags, KIT slots padded to 16): A-fragment layout
__global__ void prep_w(const float* __restrict__ wih0, const float* __restrict__ wih,
                       const float* __restrict__ whh, unsigned char* __restrict__ wf)
{
  int idx = blockIdx.x*256 + threadIdx.x;          // 6*16*4*16*64 = 393216
  int lane = idx & 63;
  int kt   = (idx >> 6) & 15;
  int q    = (idx >> 10) & 3;
  int s    = (idx >> 12) & 15;
  int l    = idx >> 16;
  if (l >= NLAYER) return;
  const int KX = (l == 0) ? DIN : NH;
  if (kt*32 >= KX + NH) return;                     // l==0: kt 12..15 unused
  int k0  = kt*32 + (lane >> 4)*8;
  int row = q*NH + s*16 + (lane & 15);
  const float* src;
  if (k0 < KX){
    src = (l == 0) ? (wih0 + (size_t)row*DIN + k0)
                   : (wih + (size_t)(l-1)*(4*NH*NH) + (size_t)row*NH + k0);
  } else {
    src = whh + (size_t)l*(4*NH*NH) + (size_t)row*NH + (k0 - KX);
  }
  f32x4 a = *(const f32x4*)src;
  f32x4 b = *(const f32x4*)(src+4);
  ulonglong2 v;
  v.x = f2bf4(a[0],a[1],a[2],a[3]);
  v.y = f2bf4(b[0],b[1],b[2],b[3]);
  *(ulonglong2*)(wf + (size_t)idx*16) = v;
}

// xf[t][g][wv][kt][lane] (16B frags): B-fragment layout of x
__global__ void prep_x(const float* __restrict__ x, unsigned char* __restrict__ xf)
{
  int idx = blockIdx.x*256 + threadIdx.x;          // 512*2*4*4*64 = 1048576
  int lane = idx & 63;
  int kt   = (idx >> 6) & 3;
  int wv   = (idx >> 8) & 3;
  int g    = (idx >> 10) & 1;
  int t    = idx >> 11;
  int b    = g*64 + wv*16 + (lane & 15);
  int k    = kt*32 + (lane >> 4)*8;
  const float* src = x + ((size_t)b*NT + t)*DIN + k;
  f32x4 a = *(const f32x4*)src;
  f32x4 c = *(const f32x4*)(src+4);
  ulonglong2 v;
  v.x = f2bf4(a[0],a[1],a[2],a[3]);
  v.y = f2bf4(c[0],c[1],c[2],c[3]);
  *(ulonglong2*)(xf + (size_t)idx*16) = v;
}

// ---------------- main: wave-dataflow LSTM, weights resident in VGPRs ----------------
template<int NKX, int KIT>
__device__ __forceinline__ void lstm_run(
    const unsigned char* __restrict__ wf,   // this (l,s) weight frags
    const unsigned char* __restrict__ xf,   // x frags (l==0 only)
    const float* __restrict__ h0, const float* __restrict__ c0,
    const float* __restrict__ bi, const float* __restrict__ bh,
    float* __restrict__ out,
    int* __restrict__ tags, int* __restrict__ acks,
    unsigned long long* __restrict__ ring,
    int Wv, int l, int s, int g, int wv, int lane)
{
  constexpr int NKH = KIT - NKX;         // 8
  const int l15  = lane & 15;
  const int quad = lane >> 4;
  const int bloc = g*64 + wv*16 + l15;
  const int jcol = s*16 + quad*4;
  const int Wm   = Wv - 1;

  // ---- A fragments: load once, make opaque (no remat), stay in VGPRs ----
  unsigned long long Au[4][KIT][2];
  #pragma unroll
  for (int q = 0; q < 4; ++q){
    #pragma unroll
    for (int kt = 0; kt < KIT; ++kt){
      ulonglong2 v = *(const ulonglong2*)(wf + ((size_t)(q*16 + kt)*64 + lane)*16);
      asm volatile("" : "+v"(v.x), "+v"(v.y));
      Au[q][kt][0] = v.x; Au[q][kt][1] = v.y;
    }
  }

  f32x4 bsv[4];
  #pragma unroll
  for (int q = 0; q < 4; ++q){
    f32x4 a = *(const f32x4*)(bi + q*NH + jcol);
    f32x4 b = *(const f32x4*)(bh + q*NH + jcol);
    bsv[q] = a + b;
  }
  float cc[4];
  {
    f32x4 cv = *(const f32x4*)(c0 + ((size_t)l*NB + bloc)*NH + jcol);
    cc[0]=cv[0]; cc[1]=cv[1]; cc[2]=cv[2]; cc[3]=cv[3];
  }

  int* tagOwn  = tags + ((l*2 + g)*Wv)*64;                 // [slot][wv][s]
  int* tagPrev = tags + (((l > 0 ? l-1 : 0)*2 + g)*Wv)*64;
  int* ackOwn  = acks + ((l*2 + g)*Wv)*64;
  int* ackPrev = acks + (((l > 0 ? l-1 : 0)*2 + g)*Wv)*64;
  const unsigned long long* ringPrev = ring + (size_t)(l > 0 ? l-1 : 0)*Wv*SLOT_U64;
  unsigned long long*       ringOwn  = ring + (size_t)l*Wv*SLOT_U64;
  const bool lastL = (l == NLAYER-1);
  const bool bp    = (Wv < NT);

  for (int t = 0; t < NT; ++t){
    const int slot  = t & Wm;
    const int pslot = (t-1) & Wm;

    if (bp && !lastL && t >= Wv) poll_ge16(ackOwn + slot*64 + wv*16, t - Wv + 1, lane);

    // ---- x-part B fragments (pure 16B/8B loads, no conversion) ----
    short8 Bx[NKX];
    if constexpr (NKX == 4){
      const unsigned char* px = xf + ((size_t)((t*2 + g)*4 + wv))*4096 + lane*16;
      #pragma unroll
      for (int k = 0; k < NKX; ++k){
        ulonglong2 v = *(const ulonglong2*)(px + k*1024);
        Bx[k] = pack16(v.x, v.y);
      }
    } else {
      poll_ge16(tagPrev + slot*64 + wv*16, t+1, lane);
      asm volatile("" ::: "memory");
      const unsigned long long* pb = ringPrev + (size_t)slot*SLOT_U64 + (size_t)bloc*64 + quad*2;
      #pragma unroll
      for (int k = 0; k < NKX; ++k) Bx[k] = pack16(ring_ld(pb + k*8), ring_ld(pb + k*8 + 1));
    }

    // ---- own-layer h fragments (critical wait) ----
    short8 Bh[NKH];
    if (t == 0){
      const float* ph = h0 + ((size_t)l*NB + bloc)*NH + quad*8;
      #pragma unroll
      for (int k = 0; k < NKH; ++k) Bh[k] = ld8f_frag(ph + k*32);
    } else {
      poll_ge16(tagOwn + pslot*64 + wv*16, t, lane);
      asm volatile("" ::: "memory");
      const unsigned long long* pb = ringOwn + (size_t)pslot*SLOT_U64 + (size_t)bloc*64 + quad*2;
      #pragma unroll
      for (int k = 0; k < NKH; ++k) Bh[k] = pack16(ring_ld(pb + k*8), ring_ld(pb + k*8 + 1));
    }

    // ---- MFMAs: x-part first (hides h-load latency), then h-part ----
    f32x4 a0 = {0,0,0,0}, a1 = {0,0,0,0}, a2 = {0,0,0,0}, a3 = {0,0,0,0};
    #pragma unroll
    for (int k = 0; k < NKX; ++k){
      a0 = __builtin_amdgcn_mfma_f32_16x16x32_bf16(pack16(Au[0][k][0],Au[0][k][1]), Bx[k], a0, 0, 0, 0);
      a1 = __builtin_amdgcn_mfma_f32_16x16x32_bf16(pack16(Au[1][k][0],Au[1][k][1]), Bx[k], a1, 0, 0, 0);
      a2 = __builtin_amdgcn_mfma_f32_16x16x32_bf16(pack16(Au[2][k][0],Au[2][k][1]), Bx[k], a2, 0, 0, 0);
      a3 = __builtin_amdgcn_mfma_f32_16x16x32_bf16(pack16(Au[3][k][0],Au[3][k][1]), Bx[k], a3, 0, 0, 0);
    }
    if constexpr (NKX == 8){
      if (bp){
        asm volatile("s_waitcnt vmcnt(0)" ::: "memory");
        if (lane == 0) st_flag(ackPrev + slot*64 + wv*16 + s, t+1);
      }
    }
    #pragma unroll
    for (int k = 0; k < NKH; ++k){
      a0 = __builtin_amdgcn_mfma_f32_16x16x32_bf16(pack16(Au[0][NKX+k][0],Au[0][NKX+k][1]), Bh[k], a0, 0, 0, 0);
      a1 = __builtin_amdgcn_mfma_f32_16x16x32_bf16(pack16(Au[1][NKX+k][0],Au[1][NKX+k][1]), Bh[k], a1, 0, 0, 0);
      a2 = __builtin_amdgcn_mfma_f32_16x16x32_bf16(pack16(Au[2][NKX+k][0],Au[2][NKX+k][1]), Bh[k], a2, 0, 0, 0);
      a3 = __builtin_amdgcn_mfma_f32_16x16x32_bf16(pack16(Au[3][NKX+k][0],Au[3][NKX+k][1]), Bh[k], a3, 0, 0, 0);
    }

    // ---- fused gate nonlinearities + state update ----
    float hv[4];
    #pragma unroll
    for (int r = 0; r < 4; ++r){
      float ig = sigmf(a0[r] + bsv[0][r]);
      float fg = sigmf(a1[r] + bsv[1][r]);
      float gv = tanhfast(a2[r] + bsv[2][r]);
      float og = sigmf(a3[r] + bsv[3][r]);
      float cn = fg*cc[r] + ig*gv;
      cc[r] = cn;
      hv[r] = og * tanhfast(cn);
    }

    // ---- publish: 8B device-coherent store, drain, per-wave tag ----
    ring_st(ringOwn + (size_t)slot*SLOT_U64 + (size_t)bloc*64 + s*4 + quad,
            f2bf4(hv[0], hv[1], hv[2], hv[3]));
    if (t == NT-1){
      f32x4 ov; ov[0]=hv[0]; ov[1]=hv[1]; ov[2]=hv[2]; ov[3]=hv[3];
      *(f32x4*)(out + ((size_t)l*NB + bloc)*NH + jcol) = ov;
    }
    asm volatile("s_waitcnt vmcnt(0)" ::: "memory");
    if (lane == 0) st_flag(tagOwn + slot*64 + wv*16 + s, t+1);
  }
}

__global__ __launch_bounds__(256, 1)
void lstm_pipe(const unsigned char* __restrict__ wf, const unsigned char* __restrict__ xf,
               const float* __restrict__ h0,  const float* __restrict__ c0,
               const float* __restrict__ bih, const float* __restrict__ bhh,
               float* __restrict__ out, int* __restrict__ tags, int* __restrict__ acks,
               unsigned long long* __restrict__ ring, int Wv)
{
  const int tid  = threadIdx.x;
  const int bid  = blockIdx.x;
  const int l    = bid >> 5;          // 32 blocks per layer
  const int s    = (bid >> 1) & 15;
  const int g    = bid & 1;
  const int lane = tid & 63;
  const int wv   = tid >> 6;

  const unsigned char* wfl = wf + (size_t)(l*16 + s)*65536;
  if (l == 0)
    lstm_run<4,12>(wfl, xf, h0, c0, bih, bhh,
                   out, tags, acks, ring, Wv, 0, s, g, wv, lane);
  else
    lstm_run<8,16>(wfl, xf, h0, c0,
                   bih + (size_t)l*(4*NH), bhh + (size_t)l*(4*NH),
                   out, tags, acks, ring, Wv, l, s, g, wv, lane);
}

extern "C" void kernel_launch(void* const* d_in, const int* in_sizes, int n_in,
                              void* d_out, int out_size, void* d_ws, size_t ws_size,
                              hipStream_t stream)
{
  (void)in_sizes; (void)n_in; (void)out_size;
  const float* x    = (const float*)d_in[0];
  const float* h0   = (const float*)d_in[1];
  const float* c0   = (const float*)d_in[2];
  const float* wih0 = (const float*)d_in[3];
  const float* wih  = (const float*)d_in[4];
  const float* whh  = (const float*)d_in[5];
  const float* bih  = (const float*)d_in[6];
  const float* bhh  = (const float*)d_in[7];

  // full-depth ring preferred; shrink if ws small (activates WAR/ack machinery)
  int Wv = NT;
  size_t tagB;
  for (;;){
    tagB = (size_t)NLAYER*2*Wv*64*4;
    size_t ringB = (size_t)NLAYER*Wv*SLOT_U64*8;
    if (2*tagB + WF_BYTES + XF_BYTES + ringB <= ws_size || Wv <= 4) break;
    Wv >>= 1;
  }

  char* p = (char*)d_ws;
  int* tags = (int*)p;                 p += tagB;
  int* acks = (int*)p;                 p += tagB;
  unsigned char* wf = (unsigned char*)p; p += WF_BYTES;
  unsigned char* xf = (unsigned char*)p; p += XF_BYTES;
  unsigned long long* ring = (unsigned long long*)p;

  (void)hipMemsetAsync(d_ws, 0, 2*tagB, stream);
  hipLaunchKernelGGL(prep_w, dim3(1536), dim3(256), 0, stream, wih0, wih, whh, wf);
  hipLaunchKernelGGL(prep_x, dim3(4096), dim3(256), 0, stream, x, xf);
  hipLaunchKernelGGL(lstm_pipe, dim3(NBLK), dim3(256), 0, stream,
                     wf, xf, h0, c0, bih, bhh,
                     (float*)d_out, tags, acks, ring, Wv);
}